// Round 1
// baseline (35366.632 us; speedup 1.0000x reference)
//
#include <hip/hip_runtime.h>
#include <hip/hip_bf16.h>

typedef __attribute__((ext_vector_type(8))) __bf16 bf16x8;
typedef __attribute__((ext_vector_type(4))) float f32x4;
typedef unsigned short u16;
typedef unsigned int u32;

#define NB 64      // batch
#define NT 512     // timesteps
#define NH 1024    // hidden
#define NOB 256    // obs dim
#define NWG 256    // persistent workgroups
#define G4H 4096   // 4*NH

__device__ __forceinline__ u16 f2bf(float f) {
  __hip_bfloat16 h = __float2bfloat16(f);
  return *reinterpret_cast<u16*>(&h);
}
__device__ __forceinline__ float sigm(float x) { return 1.f / (1.f + __expf(-x)); }
__device__ __forceinline__ float tanh_f(float x) {
  float e = __expf(2.f * x);
  return 1.f - 2.f / (e + 1.f);
}

// Grid barrier across NWG co-resident workgroups (sense via monotone generation).
// Producers' stores are drained by __syncthreads (vmcnt0); thread0 does agent
// release fence (buffer_wbl2 -> LLC) before arrival, acquire fence (buffer_inv)
// after release so the whole CU's L1/L2 view is fresh.
__device__ __forceinline__ void gridbar(int* bar, int* genc) {
  __syncthreads();
  if (threadIdx.x == 0) {
    int tgt = *genc + 1;
    __builtin_amdgcn_fence(__ATOMIC_RELEASE, "agent");
    int old = __hip_atomic_fetch_add(&bar[0], 1, __ATOMIC_RELAXED, __HIP_MEMORY_SCOPE_AGENT);
    if (old == NWG - 1) {
      __hip_atomic_store(&bar[0], 0, __ATOMIC_RELAXED, __HIP_MEMORY_SCOPE_AGENT);
      __hip_atomic_store(&bar[1], tgt, __ATOMIC_RELEASE, __HIP_MEMORY_SCOPE_AGENT);
    } else {
      while (__hip_atomic_load(&bar[1], __ATOMIC_RELAXED, __HIP_MEMORY_SCOPE_AGENT) < tgt) {
        __builtin_amdgcn_s_sleep(1);
      }
    }
    __builtin_amdgcn_fence(__ATOMIC_ACQUIRE, "agent");
  }
  __syncthreads();
  ++(*genc);
}

// Pack W = [Wih | Whh] (fp32) into bf16 MFMA B-fragments:
// frag idx = (((slice*2+nt)*2+kh)*KT2 + kt)*64 + lane ; 8 bf16 per frag.
// Element: out = slice*32+nt*16+(lane&15), k = kh*(K/2)+kt*32+(lane>>4)*8+j.
template<int KIN>
__global__ void __launch_bounds__(256)
pack_weights(const float* __restrict__ Wih, const float* __restrict__ Whh,
             u16* __restrict__ wp) {
  constexpr int K = KIN + NH;
  constexpr int KT2 = K / 64;
  const int total = 128 * 2 * 2 * KT2 * 64;
  for (int idx = blockIdx.x * blockDim.x + threadIdx.x; idx < total;
       idx += gridDim.x * blockDim.x) {
    int lane = idx & 63;
    int q = idx >> 6;
    int kt = q % KT2; q /= KT2;
    int kh = q & 1; q >>= 1;
    int nt = q & 1; q >>= 1;
    int slice = q;
    int outr = slice * 32 + nt * 16 + (lane & 15);
    int k0 = kh * (K / 2) + kt * 32 + (lane >> 4) * 8;
    union { u16 u[8]; int4 qv; } vv;
#pragma unroll
    for (int j = 0; j < 8; ++j) {
      int k = k0 + j;
      float f = (k < KIN) ? Wih[(long)outr * KIN + k] : Whh[(long)outr * NH + (k - KIN)];
      vv.u[j] = f2bf(f);
    }
    reinterpret_cast<int4*>(wp)[idx] = vv.qv;
  }
}

// obsT[t][b][k] = bf16(obs[b][t][k])
__global__ void __launch_bounds__(256)
transpose_obs(const float* __restrict__ obs, u16* __restrict__ obsT) {
  long idx = (long)blockIdx.x * blockDim.x + threadIdx.x;
  if (idx >= (long)NT * NB * NOB) return;
  int k = (int)(idx & (NOB - 1));
  long r = idx >> 8;
  int b = (int)(r & (NB - 1));
  int t = (int)(r >> 6);
  obsT[idx] = f2bf(obs[((long)b * NT + t) * NOB + k]);
}

// Persistent per-layer kernel. 256 WGs x 512 threads.
// WG = (bg = wg>>7 in {0,1}: 32 batch rows) x (slice = wg&127: 32 outputs).
// Waves: mt=wave&1 (b-half), nt=(wave>>1)&1 (out-half), kh=wave>>2 (K-half).
// Weights persistent in VGPRs; X=[x(t);h(t-1)] staged in swizzled LDS each step.
// Blocks 0..63 additionally own batch row b=wg in the elementwise phase.
template<int KIN>
__global__ void __launch_bounds__(512)
lstm_layer(const u16* __restrict__ xsrc, const u16* __restrict__ wpack,
           const float* __restrict__ bias, const float* __restrict__ gnorm,
           const float* __restrict__ cnorm,
           u16* __restrict__ hbuf, long long hstep,
           float* __restrict__ zbuf, float* __restrict__ feat, int write_feat,
           int* __restrict__ bar) {
  constexpr int K = KIN + NH;
  constexpr int KT2 = K / 64;   // k-tiles per kh half
  constexpr int CPR = K / 8;    // 16B chunks per LDS row
  constexpr int ROWB = K * 2;   // bytes per LDS row
  extern __shared__ char smem[];
  char* xs = smem;                                           // 32 * ROWB bytes
  float* sred = reinterpret_cast<float*>(smem + 32 * ROWB);  // 1024 floats

  const int tid = threadIdx.x;
  const int lane = tid & 63;
  const int wave = tid >> 6;
  const int mt = wave & 1;
  const int nt = (wave >> 1) & 1;
  const int kh = wave >> 2;
  const int wg = blockIdx.x;
  const int bg = wg >> 7;
  const int slice = wg & 127;
  const int col = lane & 15;
  const int rgrp = lane >> 4;

  // ---- persistent weight fragments in VGPRs ----
  bf16x8 wf[KT2];
  {
    const bf16x8* wpb = reinterpret_cast<const bf16x8*>(wpack)
                      + ((long)((slice * 2 + nt) * 2 + kh) * KT2) * 64 + lane;
#pragma unroll
    for (int kt = 0; kt < KT2; ++kt) wf[kt] = wpb[(long)kt * 64];
  }
  const float biasv = bias[slice * 32 + nt * 16 + col];

  // ---- elementwise-phase per-thread constants/state ----
  const int ej = tid * 2;
  float gn[8];
  float cw0 = 0.f, cw1 = 0.f;  // cnorm weights
  float c0 = 0.f, c1 = 0.f;    // cell state (persistent in registers)
  if (wg < NB) {
#pragma unroll
    for (int g = 0; g < 4; ++g) {
      gn[g * 2]     = gnorm[g * NH + ej];
      gn[g * 2 + 1] = gnorm[g * NH + ej + 1];
    }
    cw0 = cnorm[ej];
    cw1 = cnorm[ej + 1];
  }

  int genc = 0;

  for (int t = 0; t < NT; ++t) {
    // -------- phase 1: stage X = [x(t) ; h(t-1)] for this batch group --------
    const u16* xt = xsrc + (long)t * (NB * KIN);
    const u16* hp = hbuf + (long)t * hstep;
#pragma unroll 1
    for (int c = tid; c < 4 * K; c += 512) {
      int r = c / CPR;
      int kc = c - r * CPR;
      int b = bg * 32 + r;
      int k0 = kc * 8;
      int4 v;
      if (k0 < KIN) v = *reinterpret_cast<const int4*>(xt + (long)b * KIN + k0);
      else          v = *reinterpret_cast<const int4*>(hp + (long)b * NH + (k0 - KIN));
      *reinterpret_cast<int4*>(xs + r * ROWB + ((kc ^ (r & 7)) << 4)) = v;
    }
    __syncthreads();

    // -------- GEMM: [16b x 16out] per wave over its K-half --------
    f32x4 acc = {0.f, 0.f, 0.f, 0.f};
    const int arow = mt * 16 + col;
    const char* abase = xs + arow * ROWB;
    const int kb = kh * (K / 2) + rgrp * 8;
#pragma unroll
    for (int kt = 0; kt < KT2; ++kt) {
      int k = kb + kt * 32;
      bf16x8 a = *reinterpret_cast<const bf16x8*>(abase + (((k >> 3) ^ (arow & 7)) << 4));
      acc = __builtin_amdgcn_mfma_f32_16x16x32_bf16(a, wf[kt], acc, 0, 0, 0);
    }
    if (kh == 1) {
      *reinterpret_cast<f32x4*>(sred + ((wave & 3) * 64 + lane) * 4) = acc;
    }
    __syncthreads();
    if (kh == 0) {
      const float* sp = sred + ((wave & 3) * 64 + lane) * 4;
      int outc = slice * 32 + nt * 16 + col;
      int brow = bg * 32 + mt * 16 + rgrp * 4;
      float* zr = zbuf + (long)brow * G4H + outc;
      zr[0 * G4H] = acc[0] + sp[0] + biasv;
      zr[1 * G4H] = acc[1] + sp[1] + biasv;
      zr[2 * G4H] = acc[2] + sp[2] + biasv;
      zr[3 * G4H] = acc[3] + sp[3] + biasv;
    }
    gridbar(bar, &genc);

    // -------- phase 2: per-row gates / state update (blocks 0..63) --------
    if (wg < NB) {
      const float2* z2 = reinterpret_cast<const float2*>(zbuf + (long)wg * G4H);
      float2 vi = z2[tid], vf = z2[512 + tid], vg = z2[1024 + tid], vo = z2[1536 + tid];
      float s0 = vi.x * vi.x + vi.y * vi.y;
      float s1 = vf.x * vf.x + vf.y * vf.y;
      float s2 = vg.x * vg.x + vg.y * vg.y;
      float s3 = vo.x * vo.x + vo.y * vo.y;
#pragma unroll
      for (int off = 32; off; off >>= 1) {
        s0 += __shfl_xor(s0, off);
        s1 += __shfl_xor(s1, off);
        s2 += __shfl_xor(s2, off);
        s3 += __shfl_xor(s3, off);
      }
      if (lane == 0) {
        float* sp = sred + wave * 4;
        sp[0] = s0; sp[1] = s1; sp[2] = s2; sp[3] = s3;
      }
      __syncthreads();
      float t0 = 0.f, t1 = 0.f, t2 = 0.f, t3 = 0.f;
#pragma unroll
      for (int w = 0; w < 8; ++w) {
        t0 += sred[w * 4 + 0]; t1 += sred[w * 4 + 1];
        t2 += sred[w * 4 + 2]; t3 += sred[w * 4 + 3];
      }
      constexpr float inv = 1.f / 1024.f;
      float r0 = rsqrtf(t0 * inv + 1e-6f);
      float r1 = rsqrtf(t1 * inv + 1e-6f);
      float r2 = rsqrtf(t2 * inv + 1e-6f);
      float r3 = rsqrtf(t3 * inv + 1e-6f);
      float i0 = sigm(vi.x * gn[0] * r0), i1 = sigm(vi.y * gn[1] * r0);
      float f0 = sigm(vf.x * gn[2] * r1), f1 = sigm(vf.y * gn[3] * r1);
      float g0 = tanh_f(vg.x * gn[4] * r2), g1 = tanh_f(vg.y * gn[5] * r2);
      float o0 = sigm(vo.x * gn[6] * r3), o1 = sigm(vo.y * gn[7] * r3);
      c0 = f0 * c0 + i0 * g0;
      c1 = f1 * c1 + i1 * g1;
      float cs = c0 * c0 + c1 * c1;
#pragma unroll
      for (int off = 32; off; off >>= 1) cs += __shfl_xor(cs, off);
      if (lane == 0) sred[32 + wave] = cs;
      __syncthreads();
      float ct = 0.f;
#pragma unroll
      for (int w = 0; w < 8; ++w) ct += sred[32 + w];
      float rc = rsqrtf(ct * inv + 1e-6f);
      float h0 = o0 * tanh_f(c0 * cw0 * rc);
      float h1 = o1 * tanh_f(c1 * cw1 * rc);
      u16* hw = hbuf + (long)(t + 1) * hstep + (long)wg * NH + ej;
      *reinterpret_cast<u32*>(hw) = (u32)f2bf(h0) | ((u32)f2bf(h1) << 16);
      if (write_feat && t == NT - 1) {
        feat[wg * NH + ej] = h0;
        feat[wg * NH + ej + 1] = h1;
      }
    }
    gridbar(bar, &genc);
  }
}

__global__ void __launch_bounds__(256)
head_kernel(const float* __restrict__ feat, const float* __restrict__ Wout,
            const float* __restrict__ bout, const float* __restrict__ stdp,
            float* __restrict__ out) {
  int b = blockIdx.x;
  int a = threadIdx.x >> 5;
  int l = threadIdx.x & 31;
  float s = 0.f;
  for (int k = l; k < NH; k += 32) s += feat[b * NH + k] * Wout[a * NH + k];
#pragma unroll
  for (int off = 16; off; off >>= 1) s += __shfl_xor(s, off, 32);
  if (l == 0) out[b * 8 + a] = s + bout[a];
  if (b == 0 && threadIdx.x < 8) {
    float x = stdp[threadIdx.x];
    float splus = (x > 20.f) ? x : log1pf(__expf(x));
    out[512 + threadIdx.x] = splus + 0.01f;
  }
}

extern "C" void kernel_launch(void* const* d_in, const int* in_sizes, int n_in,
                              void* d_out, int out_size, void* d_ws, size_t ws_size,
                              hipStream_t stream) {
  (void)in_sizes; (void)n_in; (void)out_size;
  const float* obs  = (const float*)d_in[0];
  const float* Wih0 = (const float*)d_in[1];
  const float* Whh0 = (const float*)d_in[2];
  const float* b0   = (const float*)d_in[3];
  const float* gn0  = (const float*)d_in[4];
  const float* cn0  = (const float*)d_in[5];
  const float* Wih1 = (const float*)d_in[6];
  const float* Whh1 = (const float*)d_in[7];
  const float* b1   = (const float*)d_in[8];
  const float* gn1  = (const float*)d_in[9];
  const float* cn1  = (const float*)d_in[10];
  const float* Wout = (const float*)d_in[11];
  const float* bout = (const float*)d_in[12];
  const float* stdp = (const float*)d_in[13];
  float* out = (float*)d_out;

  char* ws = (char*)d_ws;
  size_t off = 0;
  auto take = [&](size_t bytes) -> char* {
    char* p = ws + off;
    off = (off + bytes + 255) & ~(size_t)255;
    return p;
  };
  u16* wp0    = (u16*)take((size_t)G4H * 1280 * 2);        // packed [Wih0|Whh0]
  u16* wp1    = (u16*)take((size_t)G4H * 2048 * 2);        // packed [Wih1|Whh1]
  u16* obsT   = (u16*)take((size_t)NT * NB * NOB * 2);     // [T][B][OB] bf16
  u16* out0   = (u16*)take((size_t)(NT + 1) * NB * NH * 2);// h0 history, slot0=zeros
  u16* h1b    = (u16*)take((size_t)NB * NH * 2);           // h1 state
  float* zbuf = (float*)take((size_t)NB * G4H * 4);        // gate preacts
  float* feat = (float*)take((size_t)NB * NH * 4);         // final h1 fp32
  int* bars   = (int*)take(512);                           // 2 barrier pairs
  if (off > ws_size) return;  // workspace too small: bail safely

  constexpr int LDS0 = 32 * (1280 * 2) + 4096;  // 86016 B
  constexpr int LDS1 = 32 * (2048 * 2) + 4096;  // 135168 B
  (void)hipFuncSetAttribute((const void*)lstm_layer<NOB>,
                            hipFuncAttributeMaxDynamicSharedMemorySize, LDS0);
  (void)hipFuncSetAttribute((const void*)lstm_layer<NH>,
                            hipFuncAttributeMaxDynamicSharedMemorySize, LDS1);

  hipMemsetAsync(bars, 0, 512, stream);
  hipMemsetAsync(h1b, 0, (size_t)NB * NH * 2, stream);
  hipMemsetAsync(out0, 0, (size_t)NB * NH * 2, stream);  // slot 0 = h0(-1) = 0

  pack_weights<NOB><<<2560, 256, 0, stream>>>(Wih0, Whh0, wp0);
  pack_weights<NH><<<4096, 256, 0, stream>>>(Wih1, Whh1, wp1);
  transpose_obs<<<(NT * NB * NOB) / 256, 256, 0, stream>>>(obs, obsT);

  // Layer 0: x(t)=obsT[t], h history in out0 (read slot t, write slot t+1)
  lstm_layer<NOB><<<NWG, 512, LDS0, stream>>>(obsT, wp0, b0, gn0, cn0,
                                              out0, (long long)(NB * NH),
                                              zbuf, feat, 0, bars);
  // Layer 1: x(t)=h0(t)=out0 slot t+1, h1 state in-place (hstep=0)
  lstm_layer<NH><<<NWG, 512, LDS1, stream>>>(out0 + NB * NH, wp1, b1, gn1, cn1,
                                             h1b, 0LL, zbuf, feat, 1, bars + 64);

  head_kernel<<<NB, 256, 0, stream>>>(feat, Wout, bout, stdp, out);
}

// Round 2
// 10855.884 us; speedup vs baseline: 3.2578x; 3.2578x over previous
//
#include <hip/hip_runtime.h>
#include <hip/hip_bf16.h>

typedef __attribute__((ext_vector_type(8))) __bf16 bf16x8;
typedef __attribute__((ext_vector_type(4))) float f32x4;
typedef unsigned short u16;
typedef unsigned int u32;

#define NB 64      // batch
#define NT 512     // timesteps
#define NH 1024    // hidden
#define NOB 256    // obs dim
#define NWG 256    // persistent workgroups
#define G4H 4096   // 4*NH
#define BAR_LEAVES 16

#define AS_RELAXED __ATOMIC_RELAXED
#define SCOPE_AGENT __HIP_MEMORY_SCOPE_AGENT

__device__ __forceinline__ u16 f2bf(float f) {
  __hip_bfloat16 h = __float2bfloat16(f);
  return *reinterpret_cast<u16*>(&h);
}
__device__ __forceinline__ float sigm(float x) { return 1.f / (1.f + __expf(-x)); }
__device__ __forceinline__ float tanh_f(float x) {
  float e = __expf(2.f * x);
  return 1.f - 2.f / (e + 1.f);
}

// Coherent (LLC-direct, L1/L2-bypassing) 16B load for reused single-slot buffers.
__device__ __forceinline__ int4 load_b128_coh(const void* p) {
  int4 v;
  asm volatile("global_load_dwordx4 %0, %1, off sc0 sc1\n\ts_waitcnt vmcnt(0)"
               : "=v"(v) : "v"(p) : "memory");
  return v;
}

// Fence-free grid barrier: monotonic counters, 16-leaf arrival tree, relaxed
// release store, relaxed spin. Correctness: every WG's shared stores are sc1
// (write-through to LLC) and are drained by __syncthreads' vmcnt(0) BEFORE the
// leaf atomicAdd reaches the LLC; observing the release value therefore
// transitively implies all data is visible at the LLC. Consumers read shared
// data either at fresh addresses (never cached) or with sc1 loads — so no L2
// invalidate is needed. This removes the buffer_wbl2/buffer_inv per WG per
// barrier that made round 1 re-fetch 2.7MB/step from HBM.
__device__ __forceinline__ void gridbar(int* bar, int gen) {
  __syncthreads();   // intra-WG sync + s_waitcnt vmcnt(0) lgkmcnt(0)
  if (threadIdx.x == 0) {
    const int leaf = blockIdx.x & (BAR_LEAVES - 1);
    constexpr int PER_LEAF = NWG / BAR_LEAVES;
    int old = __hip_atomic_fetch_add(&bar[leaf * 32], 1, AS_RELAXED, SCOPE_AGENT);
    if ((old & (PER_LEAF - 1)) == PER_LEAF - 1) {
      int mold = __hip_atomic_fetch_add(&bar[BAR_LEAVES * 32], 1, AS_RELAXED, SCOPE_AGENT);
      if ((mold & (BAR_LEAVES - 1)) == BAR_LEAVES - 1) {
        __hip_atomic_store(&bar[BAR_LEAVES * 32 + 32], gen, AS_RELAXED, SCOPE_AGENT);
      }
    }
    while (__hip_atomic_load(&bar[BAR_LEAVES * 32 + 32], AS_RELAXED, SCOPE_AGENT) < gen) {
      __builtin_amdgcn_s_sleep(1);
    }
  }
  __syncthreads();
}

// Pack W = [Wih | Whh] (fp32) into bf16 MFMA B-fragments:
// frag idx = (((slice*2+nt)*2+kh)*KT2 + kt)*64 + lane ; 8 bf16 per frag.
// Element: out = slice*32+nt*16+(lane&15), k = kh*(K/2)+kt*32+(lane>>4)*8+j.
template<int KIN>
__global__ void __launch_bounds__(256)
pack_weights(const float* __restrict__ Wih, const float* __restrict__ Whh,
             u16* __restrict__ wp) {
  constexpr int K = KIN + NH;
  constexpr int KT2 = K / 64;
  const int total = 128 * 2 * 2 * KT2 * 64;
  for (int idx = blockIdx.x * blockDim.x + threadIdx.x; idx < total;
       idx += gridDim.x * blockDim.x) {
    int lane = idx & 63;
    int q = idx >> 6;
    int kt = q % KT2; q /= KT2;
    int kh = q & 1; q >>= 1;
    int nt = q & 1; q >>= 1;
    int slice = q;
    int outr = slice * 32 + nt * 16 + (lane & 15);
    int k0 = kh * (K / 2) + kt * 32 + (lane >> 4) * 8;
    union { u16 u[8]; int4 qv; } vv;
#pragma unroll
    for (int j = 0; j < 8; ++j) {
      int k = k0 + j;
      float f = (k < KIN) ? Wih[(long)outr * KIN + k] : Whh[(long)outr * NH + (k - KIN)];
      vv.u[j] = f2bf(f);
    }
    reinterpret_cast<int4*>(wp)[idx] = vv.qv;
  }
}

// obsT[t][b][k] = bf16(obs[b][t][k])
__global__ void __launch_bounds__(256)
transpose_obs(const float* __restrict__ obs, u16* __restrict__ obsT) {
  long idx = (long)blockIdx.x * blockDim.x + threadIdx.x;
  if (idx >= (long)NT * NB * NOB) return;
  int k = (int)(idx & (NOB - 1));
  long r = idx >> 8;
  int b = (int)(r & (NB - 1));
  int t = (int)(r >> 6);
  obsT[idx] = f2bf(obs[((long)b * NT + t) * NOB + k]);
}

// Persistent per-layer kernel. 256 WGs x 512 threads.
// WG = (bg = wg>>7 in {0,1}: 32 batch rows) x (slice = wg&127: 32 outputs).
// Waves: mt=wave&1 (b-half), nt=(wave>>1)&1 (out-half), kh=wave>>2 (K-half).
// Weights persistent in VGPRs; X=[x(t);h(t-1)] staged in swizzled LDS each step.
// Blocks 0..63 additionally own batch row b=wg in the elementwise phase.
// HCOH=true: h buffer is a reused single slot -> stage its rows with sc1 loads.
// HCOH=false: h buffer is a per-step history -> fresh addresses, cached loads.
template<int KIN, bool HCOH>
__global__ void __launch_bounds__(512)
lstm_layer(const u16* __restrict__ xsrc, const u16* __restrict__ wpack,
           const float* __restrict__ bias, const float* __restrict__ gnorm,
           const float* __restrict__ cnorm,
           u16* __restrict__ hbuf, long long hstep,
           float* __restrict__ zbuf, float* __restrict__ feat, int write_feat,
           int* __restrict__ bar) {
  constexpr int K = KIN + NH;
  constexpr int KT2 = K / 64;   // k-tiles per kh half
  constexpr int CPR = K / 8;    // 16B chunks per LDS row
  constexpr int ROWB = K * 2;   // bytes per LDS row
  extern __shared__ char smem[];
  char* xs = smem;                                           // 32 * ROWB bytes
  float* sred = reinterpret_cast<float*>(smem + 32 * ROWB);  // 1024 floats

  const int tid = threadIdx.x;
  const int lane = tid & 63;
  const int wave = tid >> 6;
  const int mt = wave & 1;
  const int nt = (wave >> 1) & 1;
  const int kh = wave >> 2;
  const int wg = blockIdx.x;
  const int bg = wg >> 7;
  const int slice = wg & 127;
  const int col = lane & 15;
  const int rgrp = lane >> 4;

  // ---- persistent weight fragments in VGPRs ----
  bf16x8 wf[KT2];
  {
    const bf16x8* wpb = reinterpret_cast<const bf16x8*>(wpack)
                      + ((long)((slice * 2 + nt) * 2 + kh) * KT2) * 64 + lane;
#pragma unroll
    for (int kt = 0; kt < KT2; ++kt) wf[kt] = wpb[(long)kt * 64];
  }
  const float biasv = bias[slice * 32 + nt * 16 + col];

  // ---- elementwise-phase per-thread constants/state ----
  const int ej = tid * 2;
  float gn[8];
  float cw0 = 0.f, cw1 = 0.f;  // cnorm weights
  float c0 = 0.f, c1 = 0.f;    // cell state (persistent in registers)
  if (wg < NB) {
#pragma unroll
    for (int g = 0; g < 4; ++g) {
      gn[g * 2]     = gnorm[g * NH + ej];
      gn[g * 2 + 1] = gnorm[g * NH + ej + 1];
    }
    cw0 = cnorm[ej];
    cw1 = cnorm[ej + 1];
  }

  int gen = 0;

  for (int t = 0; t < NT; ++t) {
    // -------- phase 1: stage X = [x(t) ; h(t-1)] for this batch group --------
    const u16* xt = xsrc + (long)t * (NB * KIN);
    const u16* hp = hbuf + (long)t * hstep;
#pragma unroll 1
    for (int c = tid; c < 4 * K; c += 512) {
      int r = c / CPR;
      int kc = c - r * CPR;
      int b = bg * 32 + r;
      int k0 = kc * 8;
      int4 v;
      if (k0 < KIN) {
        v = *reinterpret_cast<const int4*>(xt + (long)b * KIN + k0);
      } else {
        const void* hp2 = hp + (long)b * NH + (k0 - KIN);
        if constexpr (HCOH) v = load_b128_coh(hp2);
        else                v = *reinterpret_cast<const int4*>(hp2);
      }
      *reinterpret_cast<int4*>(xs + r * ROWB + ((kc ^ (r & 7)) << 4)) = v;
    }
    __syncthreads();

    // -------- GEMM: [16b x 16out] per wave over its K-half --------
    f32x4 acc = {0.f, 0.f, 0.f, 0.f};
    const int arow = mt * 16 + col;
    const char* abase = xs + arow * ROWB;
    const int kb = kh * (K / 2) + rgrp * 8;
#pragma unroll
    for (int kt = 0; kt < KT2; ++kt) {
      int k = kb + kt * 32;
      bf16x8 a = *reinterpret_cast<const bf16x8*>(abase + (((k >> 3) ^ (arow & 7)) << 4));
      acc = __builtin_amdgcn_mfma_f32_16x16x32_bf16(a, wf[kt], acc, 0, 0, 0);
    }
    if (kh == 1) {
      *reinterpret_cast<f32x4*>(sred + ((wave & 3) * 64 + lane) * 4) = acc;
    }
    __syncthreads();
    if (kh == 0) {
      const float* sp = sred + ((wave & 3) * 64 + lane) * 4;
      int outc = slice * 32 + nt * 16 + col;
      int brow = bg * 32 + mt * 16 + rgrp * 4;
      float* zr = zbuf + (long)brow * G4H + outc;
      __hip_atomic_store(&zr[0 * G4H], acc[0] + sp[0] + biasv, AS_RELAXED, SCOPE_AGENT);
      __hip_atomic_store(&zr[1 * G4H], acc[1] + sp[1] + biasv, AS_RELAXED, SCOPE_AGENT);
      __hip_atomic_store(&zr[2 * G4H], acc[2] + sp[2] + biasv, AS_RELAXED, SCOPE_AGENT);
      __hip_atomic_store(&zr[3 * G4H], acc[3] + sp[3] + biasv, AS_RELAXED, SCOPE_AGENT);
    }
    gridbar(bar, ++gen);

    // -------- phase 2: per-row gates / state update (blocks 0..63) --------
    if (wg < NB) {
      const float* zp = zbuf + (long)wg * G4H;
      float vix = __hip_atomic_load(&zp[2 * tid],        AS_RELAXED, SCOPE_AGENT);
      float viy = __hip_atomic_load(&zp[2 * tid + 1],    AS_RELAXED, SCOPE_AGENT);
      float vfx = __hip_atomic_load(&zp[1024 + 2 * tid],     AS_RELAXED, SCOPE_AGENT);
      float vfy = __hip_atomic_load(&zp[1024 + 2 * tid + 1], AS_RELAXED, SCOPE_AGENT);
      float vgx = __hip_atomic_load(&zp[2048 + 2 * tid],     AS_RELAXED, SCOPE_AGENT);
      float vgy = __hip_atomic_load(&zp[2048 + 2 * tid + 1], AS_RELAXED, SCOPE_AGENT);
      float vox = __hip_atomic_load(&zp[3072 + 2 * tid],     AS_RELAXED, SCOPE_AGENT);
      float voy = __hip_atomic_load(&zp[3072 + 2 * tid + 1], AS_RELAXED, SCOPE_AGENT);
      float s0 = vix * vix + viy * viy;
      float s1 = vfx * vfx + vfy * vfy;
      float s2 = vgx * vgx + vgy * vgy;
      float s3 = vox * vox + voy * voy;
#pragma unroll
      for (int off = 32; off; off >>= 1) {
        s0 += __shfl_xor(s0, off);
        s1 += __shfl_xor(s1, off);
        s2 += __shfl_xor(s2, off);
        s3 += __shfl_xor(s3, off);
      }
      if (lane == 0) {
        float* sp = sred + wave * 4;
        sp[0] = s0; sp[1] = s1; sp[2] = s2; sp[3] = s3;
      }
      __syncthreads();
      float t0 = 0.f, t1 = 0.f, t2 = 0.f, t3 = 0.f;
#pragma unroll
      for (int w = 0; w < 8; ++w) {
        t0 += sred[w * 4 + 0]; t1 += sred[w * 4 + 1];
        t2 += sred[w * 4 + 2]; t3 += sred[w * 4 + 3];
      }
      constexpr float inv = 1.f / 1024.f;
      float r0 = rsqrtf(t0 * inv + 1e-6f);
      float r1 = rsqrtf(t1 * inv + 1e-6f);
      float r2 = rsqrtf(t2 * inv + 1e-6f);
      float r3 = rsqrtf(t3 * inv + 1e-6f);
      float i0 = sigm(vix * gn[0] * r0), i1 = sigm(viy * gn[1] * r0);
      float f0 = sigm(vfx * gn[2] * r1), f1 = sigm(vfy * gn[3] * r1);
      float g0 = tanh_f(vgx * gn[4] * r2), g1 = tanh_f(vgy * gn[5] * r2);
      float o0 = sigm(vox * gn[6] * r3), o1 = sigm(voy * gn[7] * r3);
      c0 = f0 * c0 + i0 * g0;
      c1 = f1 * c1 + i1 * g1;
      float cs = c0 * c0 + c1 * c1;
#pragma unroll
      for (int off = 32; off; off >>= 1) cs += __shfl_xor(cs, off);
      if (lane == 0) sred[32 + wave] = cs;
      __syncthreads();
      float ct = 0.f;
#pragma unroll
      for (int w = 0; w < 8; ++w) ct += sred[32 + w];
      float rc = rsqrtf(ct * inv + 1e-6f);
      float h0 = o0 * tanh_f(c0 * cw0 * rc);
      float h1 = o1 * tanh_f(c1 * cw1 * rc);
      u16* hw = hbuf + (long)(t + 1) * hstep + (long)wg * NH + ej;
      u32 packed = (u32)f2bf(h0) | ((u32)f2bf(h1) << 16);
      __hip_atomic_store(reinterpret_cast<u32*>(hw), packed, AS_RELAXED, SCOPE_AGENT);
      if (write_feat && t == NT - 1) {
        feat[wg * NH + ej] = h0;
        feat[wg * NH + ej + 1] = h1;
      }
    }
    gridbar(bar, ++gen);
  }
}

__global__ void __launch_bounds__(256)
head_kernel(const float* __restrict__ feat, const float* __restrict__ Wout,
            const float* __restrict__ bout, const float* __restrict__ stdp,
            float* __restrict__ out) {
  int b = blockIdx.x;
  int a = threadIdx.x >> 5;
  int l = threadIdx.x & 31;
  float s = 0.f;
  for (int k = l; k < NH; k += 32) s += feat[b * NH + k] * Wout[a * NH + k];
#pragma unroll
  for (int off = 16; off; off >>= 1) s += __shfl_xor(s, off, 32);
  if (l == 0) out[b * 8 + a] = s + bout[a];
  if (b == 0 && threadIdx.x < 8) {
    float x = stdp[threadIdx.x];
    float splus = (x > 20.f) ? x : log1pf(__expf(x));
    out[512 + threadIdx.x] = splus + 0.01f;
  }
}

extern "C" void kernel_launch(void* const* d_in, const int* in_sizes, int n_in,
                              void* d_out, int out_size, void* d_ws, size_t ws_size,
                              hipStream_t stream) {
  (void)in_sizes; (void)n_in; (void)out_size;
  const float* obs  = (const float*)d_in[0];
  const float* Wih0 = (const float*)d_in[1];
  const float* Whh0 = (const float*)d_in[2];
  const float* b0   = (const float*)d_in[3];
  const float* gn0  = (const float*)d_in[4];
  const float* cn0  = (const float*)d_in[5];
  const float* Wih1 = (const float*)d_in[6];
  const float* Whh1 = (const float*)d_in[7];
  const float* b1   = (const float*)d_in[8];
  const float* gn1  = (const float*)d_in[9];
  const float* cn1  = (const float*)d_in[10];
  const float* Wout = (const float*)d_in[11];
  const float* bout = (const float*)d_in[12];
  const float* stdp = (const float*)d_in[13];
  float* out = (float*)d_out;

  char* ws = (char*)d_ws;
  size_t off = 0;
  auto take = [&](size_t bytes) -> char* {
    char* p = ws + off;
    off = (off + bytes + 255) & ~(size_t)255;
    return p;
  };

  const size_t WP0_B   = (size_t)G4H * 1280 * 2;            // 10.49 MB
  const size_t WP1_B   = (size_t)G4H * 2048 * 2;            // 16.78 MB
  const size_t OBST_B  = (size_t)NT * NB * NOB * 2;         // 16.78 MB
  const size_t HIST_B  = (size_t)(NT + 1) * NB * NH * 2;    // 67.24 MB

  u16* wp1 = (u16*)take(WP1_B);
  // Region shared in time: {wp0 + obsT} live only during dispatch 1;
  // h1 history lives only during dispatch 2.
  const size_t wp0_obst = ((WP0_B + 255) & ~(size_t)255) + OBST_B;
  char* shared_region = take(wp0_obst > HIST_B ? wp0_obst : HIST_B);
  u16* wp0    = (u16*)shared_region;
  u16* obsT   = (u16*)(shared_region + ((WP0_B + 255) & ~(size_t)255));
  u16* h1hist = (u16*)shared_region;                        // overlays wp0+obsT
  u16* out0   = (u16*)take(HIST_B);                         // h0 history, slot0=zeros
  u16* h1b    = (u16*)take((size_t)NB * NH * 2);            // fallback single-slot h1
  float* zbuf = (float*)take((size_t)NB * G4H * 4);         // gate preacts
  float* feat = (float*)take((size_t)NB * NH * 4);          // final h1 fp32
  int* bars   = (int*)take(8192);                           // 2 barrier regions
  const bool fits = (off <= ws_size);

  // Fallback layout (round-1 footprint, known to fit): no h1 history.
  if (!fits) {
    off = 0;
    wp1  = (u16*)take(WP1_B);
    wp0  = (u16*)take(WP0_B);
    obsT = (u16*)take(OBST_B);
    out0 = (u16*)take(HIST_B);
    h1b  = (u16*)take((size_t)NB * NH * 2);
    zbuf = (float*)take((size_t)NB * G4H * 4);
    feat = (float*)take((size_t)NB * NH * 4);
    bars = (int*)take(8192);
    if (off > ws_size) return;  // hopeless; bail
  }

  constexpr int LDS0 = 32 * (1280 * 2) + 4096;  // 86016 B
  constexpr int LDS1 = 32 * (2048 * 2) + 4096;  // 135168 B
  (void)hipFuncSetAttribute((const void*)lstm_layer<NOB, false>,
                            hipFuncAttributeMaxDynamicSharedMemorySize, LDS0);
  (void)hipFuncSetAttribute((const void*)lstm_layer<NH, false>,
                            hipFuncAttributeMaxDynamicSharedMemorySize, LDS1);
  (void)hipFuncSetAttribute((const void*)lstm_layer<NH, true>,
                            hipFuncAttributeMaxDynamicSharedMemorySize, LDS1);

  hipMemsetAsync(bars, 0, 8192, stream);
  hipMemsetAsync(out0, 0, (size_t)NB * NH * 2, stream);  // slot 0 = h0(-1) = 0

  pack_weights<NOB><<<2560, 256, 0, stream>>>(Wih0, Whh0, wp0);
  pack_weights<NH><<<4096, 256, 0, stream>>>(Wih1, Whh1, wp1);
  transpose_obs<<<(NT * NB * NOB) / 256, 256, 0, stream>>>(obs, obsT);

  // Layer 0: x(t)=obsT[t], h history in out0 (read slot t, write slot t+1)
  lstm_layer<NOB, false><<<NWG, 512, LDS0, stream>>>(
      obsT, wp0, b0, gn0, cn0, out0, (long long)(NB * NH), zbuf, feat, 0, bars);

  if (fits) {
    // h1 history overlays the (now dead) wp0+obsT region; zero slot 0 AFTER
    // dispatch 1 so the memset lands on top of the stale wp0 bytes.
    hipMemsetAsync(h1hist, 0, (size_t)NB * NH * 2, stream);
    lstm_layer<NH, false><<<NWG, 512, LDS1, stream>>>(
        out0 + NB * NH, wp1, b1, gn1, cn1, h1hist, (long long)(NB * NH),
        zbuf, feat, 1, bars + 1024);
  } else {
    hipMemsetAsync(h1b, 0, (size_t)NB * NH * 2, stream);
    lstm_layer<NH, true><<<NWG, 512, LDS1, stream>>>(
        out0 + NB * NH, wp1, b1, gn1, cn1, h1b, 0LL,
        zbuf, feat, 1, bars + 1024);
  }

  head_kernel<<<NB, 256, 0, stream>>>(feat, Wout, bout, stdp, out);
}

// Round 3
// 6713.746 us; speedup vs baseline: 5.2678x; 1.6170x over previous
//
#include <hip/hip_runtime.h>
#include <hip/hip_bf16.h>

typedef __attribute__((ext_vector_type(8))) __bf16 bf16x8;
typedef __attribute__((ext_vector_type(4))) float f32x4;
typedef unsigned short u16;
typedef unsigned int u32;

#define NB 64      // batch
#define NT 512     // timesteps
#define NH 1024    // hidden
#define NOB 256    // obs dim
#define NWG 256    // persistent workgroups
#define G4H 4096   // 4*NH
#define BH (NB*NH) // h-slot elements
#define BAR_LEAVES 16

// LDS segment layout (per-WG): X = [obs 32x256 | h0 32x1024 | h1 32x1024] bf16
#define S_OBS 0
#define S_H0  16384
#define S_H1  81920
#define LDS_TOTAL 147456

#define KT0 10   // k-tiles per wave, layer 0 (K=1280 / 4 kq / 32)
#define KT1 16   // k-tiles per wave, layer 1 (K=2048 / 4 kq / 32)

#define AS_RELAXED __ATOMIC_RELAXED
#define SCOPE_AGENT __HIP_MEMORY_SCOPE_AGENT

#define KEEPW(x) asm volatile("" : "+v"(x))

__device__ __forceinline__ u16 f2bf(float f) {
  __hip_bfloat16 h = __float2bfloat16(f);
  return *reinterpret_cast<u16*>(&h);
}
__device__ __forceinline__ float sigm(float x) { return 1.f / (1.f + __expf(-x)); }
__device__ __forceinline__ float tanh_f(float x) {
  float e = __expf(2.f * x);
  return 1.f - 2.f / (e + 1.f);
}

// Coherent (LLC-direct) 16B load for reused single-slot buffers (fallback path).
__device__ __forceinline__ int4 load_b128_coh(const void* p) {
  int4 v;
  asm volatile("global_load_dwordx4 %0, %1, off sc0 sc1\n\ts_waitcnt vmcnt(0)"
               : "=v"(v) : "v"(p) : "memory");
  return v;
}

// Fence-free grid barrier (see round-2 notes): sc1 write-through stores drained
// by __syncthreads' vmcnt(0) before leaf arrival; consumers read fresh addrs or
// sc1 -> no L2 maintenance needed.
__device__ __forceinline__ void gridbar(int* bar, int gen) {
  __syncthreads();
  if (threadIdx.x == 0) {
    const int leaf = blockIdx.x & (BAR_LEAVES - 1);
    constexpr int PER_LEAF = NWG / BAR_LEAVES;
    int old = __hip_atomic_fetch_add(&bar[leaf * 32], 1, AS_RELAXED, SCOPE_AGENT);
    if ((old & (PER_LEAF - 1)) == PER_LEAF - 1) {
      int mold = __hip_atomic_fetch_add(&bar[BAR_LEAVES * 32], 1, AS_RELAXED, SCOPE_AGENT);
      if ((mold & (BAR_LEAVES - 1)) == BAR_LEAVES - 1) {
        __hip_atomic_store(&bar[BAR_LEAVES * 32 + 32], gen, AS_RELAXED, SCOPE_AGENT);
      }
    }
    while (__hip_atomic_load(&bar[BAR_LEAVES * 32 + 32], AS_RELAXED, SCOPE_AGENT) < gen) {
      __builtin_amdgcn_s_sleep(1);
    }
  }
  __syncthreads();
}

// Per-wave k-tile -> absolute k in X-space.
// L0: X = [obs(256) ; h0(1024)], wave kq covers obs[kq*64, +64) then h0 quarter.
// L1: X = [h0(1024) ; h1(1024)], wave kq covers contiguous quarter.
__device__ __host__ __forceinline__ int wavek0(int kq, int kt) {
  return kt < 2 ? kq * 64 + kt * 32 : 256 + kq * 256 + (kt - 2) * 32;
}
__device__ __host__ __forceinline__ int wavek1(int kq, int kt) {
  return kq * 512 + kt * 32;
}

// Pack fp32 [Wih|Whh] into bf16 MFMA B-fragments:
// frag idx = (((slice*2+nt)*4+kq)*KT + kt)*64 + lane
// element: outr = slice*32+nt*16+(lane&15); k = wavek(kq,kt)+(lane>>4)*8+j
template<int LAYER>
__global__ void __launch_bounds__(256)
pack_weights(const float* __restrict__ Wih, const float* __restrict__ Whh,
             u16* __restrict__ wp) {
  constexpr int KT = LAYER ? KT1 : KT0;
  constexpr int KIN = LAYER ? 1024 : 256;
  const int total = 128 * 2 * 4 * KT * 64;
  for (int idx = blockIdx.x * blockDim.x + threadIdx.x; idx < total;
       idx += gridDim.x * blockDim.x) {
    int lane = idx & 63;
    int q = idx >> 6;
    int kt = q % KT; q /= KT;
    int kq = q & 3; q >>= 2;
    int nt = q & 1; q >>= 1;
    int slice = q;
    int outr = slice * 32 + nt * 16 + (lane & 15);
    int kb = (LAYER ? wavek1(kq, kt) : wavek0(kq, kt)) + (lane >> 4) * 8;
    union { u16 u[8]; int4 qv; } vv;
#pragma unroll
    for (int j = 0; j < 8; ++j) {
      int k = kb + j;
      float f = (k < KIN) ? Wih[(long)outr * KIN + k] : Whh[(long)outr * NH + (k - KIN)];
      vv.u[j] = f2bf(f);
    }
    reinterpret_cast<int4*>(wp)[idx] = vv.qv;
  }
}

// obsT[t][b][k] = bf16(obs[b][t][k])
__global__ void __launch_bounds__(256)
transpose_obs(const float* __restrict__ obs, u16* __restrict__ obsT) {
  long idx = (long)blockIdx.x * blockDim.x + threadIdx.x;
  if (idx >= (long)NT * NB * NOB) return;
  int k = (int)(idx & (NOB - 1));
  long r = idx >> 8;
  int b = (int)(r & (NB - 1));
  int t = (int)(r >> 6);
  obsT[idx] = f2bf(obs[((long)b * NT + t) * NOB + k]);
}

// Fused two-layer persistent kernel. 256 WGs x 512 threads, 1 WG/CU.
// Round r (r = 0..NT): L0 step r (if r<NT) and L1 step r-1 (if r>=1), both
// consuming only round-(r-1) phase-2 outputs. Per WG: bg = wg>>7 (32 batch
// rows), slice = wg&127 (32 outputs, same slice for both layers).
// Waves: nt = wave&1 (16-out half), kq = wave>>1 (K quarter); m in-wave loop.
// Both layers' weight fragments persistent in VGPRs (40 + 64 = 104 VGPRs).
// WGs 0..63 own L0 batch rows, 64..127 own L1 batch rows in phase 2.
template<bool H1COH>
__global__ void __launch_bounds__(512, 2)
fused_lstm(const u16* __restrict__ obsT,
           const u16* __restrict__ wp0, const u16* __restrict__ wp1,
           const float* __restrict__ b0, const float* __restrict__ gn0,
           const float* __restrict__ cn0,
           const float* __restrict__ b1, const float* __restrict__ gn1,
           const float* __restrict__ cn1,
           u16* __restrict__ h0hist, u16* __restrict__ h1buf, long long h1step,
           float* __restrict__ zbuf, float* __restrict__ feat,
           int* __restrict__ bar) {
  extern __shared__ char smem[];
  f32x4* sred = reinterpret_cast<f32x4*>(smem + S_H1);   // aliases h1-seg (dead)
  float* p2red = reinterpret_cast<float*>(smem + S_H0);  // aliases h0-seg (dead)

  const int tid = threadIdx.x;
  const int lane = tid & 63;
  const int wave = tid >> 6;
  const int nt = wave & 1;
  const int kq = wave >> 1;
  const int col = lane & 15;
  const int rgrp = lane >> 4;
  const int wg = blockIdx.x;
  const int bg = wg >> 7;
  const int slice = wg & 127;

  // ---- persistent weight fragments (both layers) ----
  bf16x8 wf0[KT0], wf1[KT1];
  {
    const bf16x8* p0 = reinterpret_cast<const bf16x8*>(wp0)
                     + (long)((slice * 2 + nt) * 4 + kq) * KT0 * 64 + lane;
#pragma unroll
    for (int kt = 0; kt < KT0; ++kt) { wf0[kt] = p0[kt * 64]; KEEPW(wf0[kt]); }
    const bf16x8* p1 = reinterpret_cast<const bf16x8*>(wp1)
                     + (long)((slice * 2 + nt) * 4 + kq) * KT1 * 64 + lane;
#pragma unroll
    for (int kt = 0; kt < KT1; ++kt) { wf1[kt] = p1[kt * 64]; KEEPW(wf1[kt]); }
  }
  const float bias0 = b0[slice * 32 + nt * 16 + col];
  const float bias1 = b1[slice * 32 + nt * 16 + col];

  // ---- phase-2 constants/state ----
  const int l2 = (wg >> 6) & 1;   // 0: layer0 rows, 1: layer1 rows
  const int prow = wg & 63;
  const int ej = tid * 2;
  float gn[8];
  float cw0 = 0.f, cw1 = 0.f;
  float c0 = 0.f, c1 = 0.f;
  if (wg < 128) {
    const float* gnp = l2 ? gn1 : gn0;
    const float* cnp = l2 ? cn1 : cn0;
#pragma unroll
    for (int g = 0; g < 4; ++g) {
      gn[g * 2]     = gnp[g * NH + ej];
      gn[g * 2 + 1] = gnp[g * NH + ej + 1];
    }
    cw0 = cnp[ej];
    cw1 = cnp[ej + 1];
  }

  // ---- prologue: stage obs(0) ----
  {
    const u16* os = obsT;
#pragma unroll
    for (int c = tid; c < 1024; c += 512) {
      int row = c >> 5, kc = c & 31;
      int4 v = *reinterpret_cast<const int4*>(os + (long)(bg * 32 + row) * NOB + kc * 8);
      *reinterpret_cast<int4*>(smem + S_OBS + row * 512 + ((kc ^ (row & 7)) << 4)) = v;
    }
  }

  int gen = 0;

  for (int r = 0; r <= NT; ++r) {
    // -------- stage h0(r-1) and h1(r-2) --------
    const u16* h0s = h0hist + (long)r * BH;
    const u16* h1s = h1buf + (long)r * h1step;
#pragma unroll 1
    for (int c = tid; c < 4096; c += 512) {
      int row = c >> 7, kc = c & 127;
      int4 v = *reinterpret_cast<const int4*>(h0s + (long)(bg * 32 + row) * NH + kc * 8);
      *reinterpret_cast<int4*>(smem + S_H0 + row * 2048 + ((kc ^ (row & 7)) << 4)) = v;
    }
#pragma unroll 1
    for (int c = tid; c < 4096; c += 512) {
      int row = c >> 7, kc = c & 127;
      const void* src = h1s + (long)(bg * 32 + row) * NH + kc * 8;
      int4 v;
      if constexpr (H1COH) v = load_b128_coh(src);
      else                 v = *reinterpret_cast<const int4*>(src);
      *reinterpret_cast<int4*>(smem + S_H1 + row * 2048 + ((kc ^ (row & 7)) << 4)) = v;
    }
    __syncthreads();

    // -------- GEMMs (both layers), per-wave K-quarter --------
    f32x4 a00 = {0,0,0,0}, a01 = {0,0,0,0};   // L0, m=0/1
    f32x4 a10 = {0,0,0,0}, a11 = {0,0,0,0};   // L1, m=0/1
    if (r < NT) {
#pragma unroll
      for (int kt = 0; kt < KT0; ++kt) {
        const int base   = (kt < 2) ? S_OBS : S_H0;
        const int rowstr = (kt < 2) ? 512 : 2048;
        const int chunk0 = (kt < 2) ? (kq * 8 + kt * 4) : (kq * 32 + (kt - 2) * 4);
        const int sw = (((chunk0 + rgrp) ^ (col & 7)) << 4);
        bf16x8 am0 = *reinterpret_cast<const bf16x8*>(smem + base + col * rowstr + sw);
        bf16x8 am1 = *reinterpret_cast<const bf16x8*>(smem + base + (16 + col) * rowstr + sw);
        a00 = __builtin_amdgcn_mfma_f32_16x16x32_bf16(am0, wf0[kt], a00, 0, 0, 0);
        a01 = __builtin_amdgcn_mfma_f32_16x16x32_bf16(am1, wf0[kt], a01, 0, 0, 0);
      }
    }
    if (r >= 1) {
      const int base = (kq < 2) ? S_H0 : S_H1;
#pragma unroll
      for (int kt = 0; kt < KT1; ++kt) {
        const int chunk0 = (kq & 1) * 64 + kt * 4;
        const int sw = (((chunk0 + rgrp) ^ (col & 7)) << 4);
        bf16x8 am0 = *reinterpret_cast<const bf16x8*>(smem + base + col * 2048 + sw);
        bf16x8 am1 = *reinterpret_cast<const bf16x8*>(smem + base + (16 + col) * 2048 + sw);
        a10 = __builtin_amdgcn_mfma_f32_16x16x32_bf16(am0, wf1[kt], a10, 0, 0, 0);
        a11 = __builtin_amdgcn_mfma_f32_16x16x32_bf16(am1, wf1[kt], a11, 0, 0, 0);
      }
    }
    __syncthreads();   // all LDS X reads done

    // -------- kq partials to LDS; prefetch obs(r+1) (overlaps bar/phase2) ----
    if (kq != 0) {
      f32x4* sp = sred + ((kq - 1) * 2 + nt) * 256 + lane;
      sp[0]   = a00;
      sp[64]  = a01;
      sp[128] = a10;
      sp[192] = a11;
    }
    if (r + 1 < NT) {
      const u16* os = obsT + (long)(r + 1) * (NB * NOB);
#pragma unroll
      for (int c = tid; c < 1024; c += 512) {
        int row = c >> 5, kc = c & 31;
        int4 v = *reinterpret_cast<const int4*>(os + (long)(bg * 32 + row) * NOB + kc * 8);
        *reinterpret_cast<int4*>(smem + S_OBS + row * 512 + ((kc ^ (row & 7)) << 4)) = v;
      }
    }
    __syncthreads();

    // -------- kq==0 waves: reduce partials, write z (sc1) --------
    if (kq == 0) {
#pragma unroll
      for (int w = 0; w < 3; ++w) {
        const f32x4* sp = sred + (w * 2 + nt) * 256 + lane;
        a00 += sp[0];
        a01 += sp[64];
        a10 += sp[128];
        a11 += sp[192];
      }
      const int outc = slice * 32 + nt * 16 + col;
      const long rbase = (long)(bg * 32 + rgrp * 4);
      if (r < NT) {
        float* zr = zbuf + rbase * G4H + outc;
#pragma unroll
        for (int j = 0; j < 4; ++j) {
          __hip_atomic_store(&zr[(long)j * G4H], a00[j] + bias0, AS_RELAXED, SCOPE_AGENT);
          __hip_atomic_store(&zr[(long)(16 + j) * G4H], a01[j] + bias0, AS_RELAXED, SCOPE_AGENT);
        }
      }
      if (r >= 1) {
        float* zr = zbuf + (long)NB * G4H + rbase * G4H + outc;
#pragma unroll
        for (int j = 0; j < 4; ++j) {
          __hip_atomic_store(&zr[(long)j * G4H], a10[j] + bias1, AS_RELAXED, SCOPE_AGENT);
          __hip_atomic_store(&zr[(long)(16 + j) * G4H], a11[j] + bias1, AS_RELAXED, SCOPE_AGENT);
        }
      }
    }
    gridbar(bar, ++gen);

    // -------- phase 2: WGs 0..127, one (layer, batch-row) each --------
    if (wg < 128 && (l2 ? (r >= 1) : (r < NT))) {
      const float* zp = zbuf + (l2 ? (long)NB * G4H : 0) + (long)prow * G4H;
      float vix = __hip_atomic_load(&zp[2 * tid],            AS_RELAXED, SCOPE_AGENT);
      float viy = __hip_atomic_load(&zp[2 * tid + 1],        AS_RELAXED, SCOPE_AGENT);
      float vfx = __hip_atomic_load(&zp[1024 + 2 * tid],     AS_RELAXED, SCOPE_AGENT);
      float vfy = __hip_atomic_load(&zp[1024 + 2 * tid + 1], AS_RELAXED, SCOPE_AGENT);
      float vgx = __hip_atomic_load(&zp[2048 + 2 * tid],     AS_RELAXED, SCOPE_AGENT);
      float vgy = __hip_atomic_load(&zp[2048 + 2 * tid + 1], AS_RELAXED, SCOPE_AGENT);
      float vox = __hip_atomic_load(&zp[3072 + 2 * tid],     AS_RELAXED, SCOPE_AGENT);
      float voy = __hip_atomic_load(&zp[3072 + 2 * tid + 1], AS_RELAXED, SCOPE_AGENT);
      float s0 = vix * vix + viy * viy;
      float s1 = vfx * vfx + vfy * vfy;
      float s2 = vgx * vgx + vgy * vgy;
      float s3 = vox * vox + voy * voy;
#pragma unroll
      for (int off = 32; off; off >>= 1) {
        s0 += __shfl_xor(s0, off);
        s1 += __shfl_xor(s1, off);
        s2 += __shfl_xor(s2, off);
        s3 += __shfl_xor(s3, off);
      }
      if (lane == 0) {
        float* sp = p2red + wave * 4;
        sp[0] = s0; sp[1] = s1; sp[2] = s2; sp[3] = s3;
      }
      __syncthreads();
      float t0 = 0.f, t1 = 0.f, t2 = 0.f, t3 = 0.f;
#pragma unroll
      for (int w = 0; w < 8; ++w) {
        t0 += p2red[w * 4 + 0]; t1 += p2red[w * 4 + 1];
        t2 += p2red[w * 4 + 2]; t3 += p2red[w * 4 + 3];
      }
      constexpr float inv = 1.f / 1024.f;
      float r0 = rsqrtf(t0 * inv + 1e-6f);
      float r1 = rsqrtf(t1 * inv + 1e-6f);
      float r2 = rsqrtf(t2 * inv + 1e-6f);
      float r3 = rsqrtf(t3 * inv + 1e-6f);
      float i0 = sigm(vix * gn[0] * r0), i1 = sigm(viy * gn[1] * r0);
      float f0 = sigm(vfx * gn[2] * r1), f1 = sigm(vfy * gn[3] * r1);
      float g0 = tanh_f(vgx * gn[4] * r2), g1 = tanh_f(vgy * gn[5] * r2);
      float o0 = sigm(vox * gn[6] * r3), o1 = sigm(voy * gn[7] * r3);
      c0 = f0 * c0 + i0 * g0;
      c1 = f1 * c1 + i1 * g1;
      float cs = c0 * c0 + c1 * c1;
#pragma unroll
      for (int off = 32; off; off >>= 1) cs += __shfl_xor(cs, off);
      if (lane == 0) p2red[32 + wave] = cs;
      __syncthreads();
      float ct = 0.f;
#pragma unroll
      for (int w = 0; w < 8; ++w) ct += p2red[32 + w];
      float rc = rsqrtf(ct * inv + 1e-6f);
      float h0v = o0 * tanh_f(c0 * cw0 * rc);
      float h1v = o1 * tanh_f(c1 * cw1 * rc);
      u16* hw;
      if (l2 == 0) hw = h0hist + (long)(r + 1) * BH + (long)prow * NH + ej;
      else         hw = h1buf + (long)(r + 1) * h1step + (long)prow * NH + ej;
      u32 packed = (u32)f2bf(h0v) | ((u32)f2bf(h1v) << 16);
      __hip_atomic_store(reinterpret_cast<u32*>(hw), packed, AS_RELAXED, SCOPE_AGENT);
      if (l2 == 1 && r == NT) {
        feat[prow * NH + ej] = h0v;
        feat[prow * NH + ej + 1] = h1v;
      }
    }
    gridbar(bar, ++gen);
  }
}

__global__ void __launch_bounds__(256)
head_kernel(const float* __restrict__ feat, const float* __restrict__ Wout,
            const float* __restrict__ bout, const float* __restrict__ stdp,
            float* __restrict__ out) {
  int b = blockIdx.x;
  int a = threadIdx.x >> 5;
  int l = threadIdx.x & 31;
  float s = 0.f;
  for (int k = l; k < NH; k += 32) s += feat[b * NH + k] * Wout[a * NH + k];
#pragma unroll
  for (int off = 16; off; off >>= 1) s += __shfl_xor(s, off, 32);
  if (l == 0) out[b * 8 + a] = s + bout[a];
  if (b == 0 && threadIdx.x < 8) {
    float x = stdp[threadIdx.x];
    float splus = (x > 20.f) ? x : log1pf(__expf(x));
    out[512 + threadIdx.x] = splus + 0.01f;
  }
}

extern "C" void kernel_launch(void* const* d_in, const int* in_sizes, int n_in,
                              void* d_out, int out_size, void* d_ws, size_t ws_size,
                              hipStream_t stream) {
  (void)in_sizes; (void)n_in; (void)out_size;
  const float* obs  = (const float*)d_in[0];
  const float* Wih0 = (const float*)d_in[1];
  const float* Whh0 = (const float*)d_in[2];
  const float* b0   = (const float*)d_in[3];
  const float* gn0  = (const float*)d_in[4];
  const float* cn0  = (const float*)d_in[5];
  const float* Wih1 = (const float*)d_in[6];
  const float* Whh1 = (const float*)d_in[7];
  const float* b1   = (const float*)d_in[8];
  const float* gn1  = (const float*)d_in[9];
  const float* cn1  = (const float*)d_in[10];
  const float* Wout = (const float*)d_in[11];
  const float* bout = (const float*)d_in[12];
  const float* stdp = (const float*)d_in[13];
  float* out = (float*)d_out;

  char* ws = (char*)d_ws;
  size_t off = 0;
  auto take = [&](size_t bytes) -> char* {
    char* p = ws + off;
    off = (off + bytes + 255) & ~(size_t)255;
    return p;
  };

  const size_t WP0_B  = (size_t)128 * 2 * 4 * KT0 * 64 * 16;  // 10.49 MB
  const size_t WP1_B  = (size_t)128 * 2 * 4 * KT1 * 64 * 16;  // 16.78 MB
  const size_t OBST_B = (size_t)NT * NB * NOB * 2;            // 16.78 MB
  const size_t H0H_B  = (size_t)(NT + 1) * BH * 2;            // 67.24 MB
  const size_t H1H_B  = (size_t)(NT + 2) * BH * 2;            // 67.37 MB

  u16* wp0    = (u16*)take(WP0_B);
  u16* wp1    = (u16*)take(WP1_B);
  u16* obsT   = (u16*)take(OBST_B);
  u16* h0hist = (u16*)take(H0H_B);
  u16* h1b    = (u16*)take(H1H_B);            // full history (preferred)
  float* zbuf = (float*)take((size_t)2 * NB * G4H * 4);
  float* feat = (float*)take((size_t)NB * NH * 4);
  int* bars   = (int*)take(8192);
  bool fits = (off <= ws_size);
  long long h1step = BH;

  if (!fits) {
    // Fallback: single-slot h1 (coherent staging loads), round-1-proven size.
    off = 0;
    wp0    = (u16*)take(WP0_B);
    wp1    = (u16*)take(WP1_B);
    obsT   = (u16*)take(OBST_B);
    h0hist = (u16*)take(H0H_B);
    h1b    = (u16*)take((size_t)BH * 2);
    zbuf   = (float*)take((size_t)2 * NB * G4H * 4);
    feat   = (float*)take((size_t)NB * NH * 4);
    bars   = (int*)take(8192);
    h1step = 0;
    if (off > ws_size) return;
  }

  (void)hipFuncSetAttribute((const void*)fused_lstm<false>,
                            hipFuncAttributeMaxDynamicSharedMemorySize, LDS_TOTAL);
  (void)hipFuncSetAttribute((const void*)fused_lstm<true>,
                            hipFuncAttributeMaxDynamicSharedMemorySize, LDS_TOTAL);

  hipMemsetAsync(bars, 0, 8192, stream);
  hipMemsetAsync(h0hist, 0, (size_t)BH * 2, stream);                    // h0(-1)=0
  hipMemsetAsync(h1b, 0, (size_t)(fits ? 2 : 1) * BH * 2, stream);      // h1(-2,-1)=0

  pack_weights<0><<<2560, 256, 0, stream>>>(Wih0, Whh0, wp0);
  pack_weights<1><<<4096, 256, 0, stream>>>(Wih1, Whh1, wp1);
  transpose_obs<<<(NT * NB * NOB) / 256, 256, 0, stream>>>(obs, obsT);

  if (fits) {
    fused_lstm<false><<<NWG, 512, LDS_TOTAL, stream>>>(
        obsT, wp0, wp1, b0, gn0, cn0, b1, gn1, cn1,
        h0hist, h1b, h1step, zbuf, feat, bars);
  } else {
    fused_lstm<true><<<NWG, 512, LDS_TOTAL, stream>>>(
        obsT, wp0, wp1, b0, gn0, cn0, b1, gn1, cn1,
        h0hist, h1b, 0LL, zbuf, feat, bars);
  }

  head_kernel<<<NB, 256, 0, stream>>>(feat, Wout, bout, stdp, out);
}